// Round 15
// baseline (28.825 us; speedup 1.0000x reference)
//
#include <hip/hip_runtime.h>
#include <hip/hip_bf16.h>
#include <cstdint>

// GraphLoss: layered lattice DAG (64 layers x 64 nodes, dense bipartite).
// result = sum(w*gold) + logsumexp over all source->sink paths of (-path weight).
//
// R15 = R14 (28.3us) with ONE change: XCD-local wpk. prep's conversion work
// runs only on wgs with bid%8==0 (32 wgs -> all XCD0 under measured
// round-robin dispatch), so wpk sits dirty in XCD0's local L2; seq's single
// wg (also XCD0) fetches at ~200cy local-L2 latency instead of ~1400cy
// remote-dirty. Placement heuristic only - correctness unaffected either way.
// Gold reduction moves to the other 224 wgs (partial[224]).
// seq = R14 verbatim (depth-10 counted-vmcnt pipeline, multiplicative renorm,
// peeled 18/16/../0 tail, zero-in-flight exit) except the 224-partial gather.
//
// Edge layout: e in [0,64): source->layer1 ; e = 64 + L*4096 + a*64 + b ;
// e = 258112 + j: layer64 node j -> sink.

typedef float v2f   __attribute__((ext_vector_type(2)));
typedef float f32x4 __attribute__((ext_vector_type(4)));
typedef unsigned int u32x4 __attribute__((ext_vector_type(4)));

#define NLV 63
#define NPACK (63 * 2048)            // packed u32 words (8KB/level)
#define SINK_BASE (64 + 63 * 4096)   // 258112
#define NGOLD 224

// ---------------------------------------------------------------------------
// prep: role-split by XCD. bid%8==0 (32 wgs, XCD0): convert w -> wpk in the
// R8-proven layout/formula (absmax 0.0). Other 224 wgs: gold partials.
// Layout: word f = L*2048 + h*1024 + t*4 + q, t in [0,256):
//   kc=(t&63)>>4, bb=16*(t>>6)+(t&15), pair k = 16kc+2*(4h+q):
//   packs bf16(exp(-w[e0])) | bf16(exp(-w[e0+64]))<<16, e0=64+L*4096+k*64+bb.
__global__ __launch_bounds__(256)
void prep_kernel(const int* __restrict__ g, const float* __restrict__ w,
                 unsigned int* __restrict__ wpk, float* __restrict__ partial, int E) {
    const int bid = blockIdx.x, tid = threadIdx.x;
    if ((bid & 7) == 0) {
        // -------- converter (XCD0): 32 wgs x 256 thr --------
        const int cid = bid >> 3;                    // 0..31
        for (int f = cid * 256 + tid; f < NPACK; f += 32 * 256) {
            const int L = f >> 11;
            const int r = f & 2047;
            const int h = (r >> 10) & 1;
            const int t = (r >> 2) & 255;
            const int q = r & 3;
            const int wvp = t >> 6, ls = t & 63;
            const int kcp = ls >> 4, bp = 16 * wvp + (ls & 15);
            const int k = 16 * kcp + 2 * (4 * h + q);
            const int e0 = 64 + L * 4096 + k * 64 + bp;
            const float x0 = __expf(-w[e0]);
            const float x1 = __expf(-w[e0 + 64]);
            uint32_t u0 = __float_as_uint(x0); u0 = (u0 + 0x7fffu + ((u0 >> 16) & 1u)) >> 16;
            uint32_t u1 = __float_as_uint(x1); u1 = (u1 + 0x7fffu + ((u1 >> 16) & 1u)) >> 16;
            wpk[f] = u0 | (u1 << 16);
        }
        return;
    }
    // -------- gold partial (224 wgs, XCDs 1-7) --------
    const int gid = bid - 1 - (bid >> 3);            // dense 0..223
    const bool is64 = (g[1] == 0);
    float s = 0.f;
    for (int e = gid * 256 + tid; e < E; e += NGOLD * 256) {
        const int idx = 3 * e + 2;
        const int gv = is64 ? g[2 * idx] : g[idx];
        s += w[e] * (float)gv;
    }
    #pragma unroll
    for (int dd = 1; dd < 64; dd <<= 1) s += __shfl_xor(s, dd, 64);
    __shared__ float lsm[4];
    const int wv = tid >> 6, ln = tid & 63;
    if (ln == 0) lsm[wv] = s;
    __syncthreads();
    if (tid == 0) partial[gid] = lsm[0] + lsm[1] + lsm[2] + lsm[3];
}

// ---------------------------------------------------------------------------
// seq: 256 threads / 4 waves (R14 verbatim). Wave wv owns nodes 16wv..16wv+15;
// lane computes the 16-term k-chunk (kc) partial for b=16wv+(l&15).
__global__ __launch_bounds__(256, 1)
void seq_kernel(const float* __restrict__ w, const unsigned int* __restrict__ wpk,
                const float* __restrict__ partial, float* __restrict__ out) {
    __shared__ __align__(16) float ubuf[2][64];
    __shared__ float P[2];
    __shared__ float slds[64];

    const int tid = threadIdx.x;
    const int wv = tid >> 6, l = tid & 63;
    const int kc = l >> 4;
    const int bb = 16 * wv + (l & 15);

    // compiler-visible loads, pinned complete before the counted-asm stream
    const float z10 = -w[0];
    float LS = z10;
    float uf = __expf(-w[bb] - z10);       // u_1[bb]; u_1[0] = 1
    float wsink = w[SINK_BASE + bb];
    float gs = 0.f;
    #pragma unroll
    for (int i = 0; i < 3; ++i) gs += partial[l + (i << 6)];
    if (l < NGOLD - 192) gs += partial[l + 192];     // 224 partials
    asm volatile("" : "+v"(LS), "+v"(uf), "+v"(wsink), "+v"(gs));

    if (l < 16) ubuf[0][bb] = uf;
    if (tid == 0) P[0] = 1.0f;

    const uint32_t voff  = (uint32_t)tid * 16u;
    const uint32_t voff2 = voff + 4096u;
    uintptr_t bcur = (uintptr_t)wpk;

    u32x4 q0a, q0b, q1a, q1b, q2a, q2b, q3a, q3b, q4a, q4b;
    u32x4 q5a, q5b, q6a, q6b, q7a, q7b, q8a, q8b, q9a, q9b;

#define LD1(DST, VO)                                                           \
    asm volatile("global_load_dwordx4 %0, %1, %2"                              \
                 : "=v"(DST) : "v"(VO), "s"(bcur))

#define ISSUE(QA, QB) do { LD1(QA, voff); LD1(QB, voff2); bcur += 8192u; } while (0)

#define BAR() do {                                                             \
    asm volatile("s_waitcnt lgkmcnt(0)" ::: "memory");                         \
    __builtin_amdgcn_s_barrier();                                              \
} while (0)

// body t: CB = t&1. Reads ubuf[CB]/P[CB], writes ubuf[CB^1]/P[CB^1].
#define BODY(QA, QB, CB, WSTR, DOISS) {                                        \
    asm volatile("s_waitcnt vmcnt(" WSTR ")" ::: "memory");                    \
    __builtin_amdgcn_sched_barrier(0);                                         \
    asm volatile("" : "+v"(QA), "+v"(QB));                                     \
    const float rho = P[CB];                                                   \
    float rc;                                                                  \
    asm("v_rcp_f32 %0, %1" : "=v"(rc) : "v"(rho));                             \
    const f32x4* uq = (const f32x4*)ubuf[CB];                                  \
    v2f acc = {0.f, 0.f};                                                      \
    _Pragma("unroll")                                                          \
    for (int m = 0; m < 4; ++m) {                                              \
        const f32x4 uu = uq[4 * kc + m];                                       \
        _Pragma("unroll")                                                      \
        for (int pp = 0; pp < 2; ++pp) {                                       \
            const int j2 = 2 * m + pp;                                         \
            const unsigned int wd = (j2 < 4) ? QA[j2] : QB[j2 - 4];            \
            v2f wp, up;                                                        \
            wp[0] = __uint_as_float(wd << 16);                                 \
            wp[1] = __uint_as_float(wd & 0xffff0000u);                         \
            up[0] = uu[2 * pp]; up[1] = uu[2 * pp + 1];                        \
            acc = __builtin_elementwise_fma(wp, up, acc);                      \
        }                                                                      \
    }                                                                          \
    float p = acc[0] + acc[1];                                                 \
    p += __shfl_xor(p, 16, 64);                                                \
    p += __shfl_xor(p, 32, 64);           /* p = y[bb] in all lanes */         \
    uf = p * rc;                                                               \
    LS += __logf(rho);                    /* off critical path */              \
    if (l < 16) ubuf[(CB) ^ 1][bb] = uf;                                       \
    if (tid == 0) P[(CB) ^ 1] = uf;                                            \
    if (DOISS) ISSUE(QA, QB);                                                  \
    BAR();                                                                     \
}

    // prologue: levels 0..9 in flight (20 loads)
    ISSUE(q0a, q0b); ISSUE(q1a, q1b); ISSUE(q2a, q2b); ISSUE(q3a, q3b);
    ISSUE(q4a, q4b); ISSUE(q5a, q5b); ISSUE(q6a, q6b); ISSUE(q7a, q7b);
    ISSUE(q8a, q8b); ISSUE(q9a, q9b);
    BAR();             // ubuf[0]/P[0] visible

    // bodies 0..49 (5 x 10-body rotation); body t consumes level t, issues t+10
    #pragma unroll 1
    for (int it = 0; it < 5; ++it) {
        BODY(q0a, q0b, 0, "18", 1)
        BODY(q1a, q1b, 1, "18", 1)
        BODY(q2a, q2b, 0, "18", 1)
        BODY(q3a, q3b, 1, "18", 1)
        BODY(q4a, q4b, 0, "18", 1)
        BODY(q5a, q5b, 1, "18", 1)
        BODY(q6a, q6b, 0, "18", 1)
        BODY(q7a, q7b, 1, "18", 1)
        BODY(q8a, q8b, 0, "18", 1)
        BODY(q9a, q9b, 1, "18", 1)
    }
    // peeled tail: bodies 50..62; last issue at body 52 (level 62);
    // exact waits leave ZERO loads in flight after body 62.
    BODY(q0a, q0b, 0, "18", 1)   // 50 -> L60
    BODY(q1a, q1b, 1, "18", 1)   // 51 -> L61
    BODY(q2a, q2b, 0, "18", 1)   // 52 -> L62
    BODY(q3a, q3b, 1, "18", 0)   // 53
    BODY(q4a, q4b, 0, "16", 0)   // 54
    BODY(q5a, q5b, 1, "14", 0)   // 55
    BODY(q6a, q6b, 0, "12", 0)   // 56
    BODY(q7a, q7b, 1, "10", 0)   // 57
    BODY(q8a, q8b, 0, "8",  0)   // 58
    BODY(q9a, q9b, 1, "6",  0)   // 59
    BODY(q0a, q0b, 0, "4",  0)   // 60
    BODY(q1a, q1b, 1, "2",  0)   // 61
    BODY(q2a, q2b, 0, "0",  0)   // 62

    // sink fold staging: m[bb] = LS + log(uf) - wsink
    const float m0 = LS + __logf(uf) - wsink;
    if (l < 16) slds[bb] = m0;
    BAR();

    if (wv == 0) {
        float m = slds[l];
        float s = 1.0f;
        #pragma unroll
        for (int d = 1; d < 64; d <<= 1) {
            const float om = __shfl_xor(m, d, 64);
            const float os = __shfl_xor(s, d, 64);
            const float nm = fmaxf(m, om);
            s = __expf(m - nm) * s + __expf(om - nm) * os;
            m = nm;
        }
        const float vsink = m + __logf(s);
        #pragma unroll
        for (int d = 1; d < 64; d <<= 1) gs += __shfl_xor(gs, d, 64);
        if (l == 0) out[0] = gs + vsink;
    }
}

extern "C" void kernel_launch(void* const* d_in, const int* in_sizes, int n_in,
                              void* d_out, int out_size, void* d_ws, size_t ws_size,
                              hipStream_t stream) {
    const int*   g = (const int*)d_in[0];
    const float* w = (const float*)d_in[1];
    float* out     = (float*)d_out;
    unsigned int* wpk = (unsigned int*)d_ws;        // 129024 u32
    float* partial = (float*)(wpk + NPACK);         // 224 floats
    const int E = in_sizes[0] / 3;                  // 258176

    prep_kernel<<<256, 256, 0, stream>>>(g, w, wpk, partial, E);
    seq_kernel<<<1, 256, 0, stream>>>(w, wpk, partial, out);
}